// Round 2
// baseline (358.362 us; speedup 1.0000x reference)
//
#include <hip/hip_runtime.h>
#include <hip/hip_bf16.h>

#define B_SZ 8
#define LSEQ 200
#define DMODEL 256
#define DINNER 512
#define DSTATE 64
#define DTRANK 16
#define ROWS (B_SZ * LSEQ)   // 1600

__device__ __forceinline__ float4 load4f(const float* p) {
    return *(const float4*)p;
}

__device__ __forceinline__ float softplusf(float x) {
    return (x > 20.f) ? x : log1pf(__expf(x));
}
__device__ __forceinline__ float siluf(float x) {
    return x / (1.f + __expf(-x));
}

// ---------------------------------------------------------------------------
// Generic tiled GEMM: C[M,N] = A[M,K] @ B[K,N] (+ optional fp32 residual)
// A,B fp32 row-major; C fp32. 64x64 tile, BK=16, 256 threads, 4x4/thread.
// M mult of 64, K mult of 16; N guarded (mult of 4).
// ---------------------------------------------------------------------------
__global__ __launch_bounds__(256) void gemm_tile(
    const float* __restrict__ A, const float* __restrict__ Bm, float* __restrict__ C,
    int M, int N, int K, const float* __restrict__ resid)
{
    __shared__ float As[16][64];
    __shared__ float Bs[16][68];   // +4 pad

    const int t  = threadIdx.x;
    const int m0 = blockIdx.y * 64;
    const int n0 = blockIdx.x * 64;
    const int tm = t >> 4;         // 0..15
    const int tn = t & 15;         // 0..15

    const int ar = t >> 2;         // A staging: row in tile 0..63
    const int ak = (t & 3) * 4;    // A staging: k offset 0,4,8,12
    const int bk = t >> 4;         // B staging: k row 0..15
    const int bn = (t & 15) * 4;   // B staging: n offset 0..60

    float acc[4][4];
#pragma unroll
    for (int i = 0; i < 4; i++)
#pragma unroll
        for (int j = 0; j < 4; j++) acc[i][j] = 0.f;

    for (int k0 = 0; k0 < K; k0 += 16) {
        float4 av = load4f(A + (size_t)(m0 + ar) * K + k0 + ak);
        int col = n0 + bn;
        float4 bv = make_float4(0.f, 0.f, 0.f, 0.f);
        if (col < N) bv = load4f(Bm + (size_t)(k0 + bk) * N + col);

        As[ak + 0][ar] = av.x;
        As[ak + 1][ar] = av.y;
        As[ak + 2][ar] = av.z;
        As[ak + 3][ar] = av.w;
        *(float4*)&Bs[bk][bn] = bv;
        __syncthreads();

#pragma unroll
        for (int k = 0; k < 16; k++) {
            float4 a4 = *(const float4*)&As[k][tm * 4];
            float4 b4 = *(const float4*)&Bs[k][tn * 4];
            float av_[4] = {a4.x, a4.y, a4.z, a4.w};
            float bv_[4] = {b4.x, b4.y, b4.z, b4.w};
#pragma unroll
            for (int i = 0; i < 4; i++)
#pragma unroll
                for (int j = 0; j < 4; j++)
                    acc[i][j] = fmaf(av_[i], bv_[j], acc[i][j]);
        }
        __syncthreads();
    }

#pragma unroll
    for (int i = 0; i < 4; i++) {
        int row = m0 + tm * 4 + i;
#pragma unroll
        for (int j = 0; j < 4; j++) {
            int col = n0 + tn * 4 + j;
            if (col < N) {
                float v = acc[i][j];
                if (resid) v += resid[(size_t)row * N + col];
                C[(size_t)row * N + col] = v;
            }
        }
    }
}

// ---------------------------------------------------------------------------
// Depthwise causal conv (width 4) + bias + silu.  xz cols 0..511 -> xm.
// ---------------------------------------------------------------------------
__global__ __launch_bounds__(256) void conv_silu_k(
    const float* __restrict__ xz, const float* __restrict__ conv_w,
    const float* __restrict__ conv_b, float* __restrict__ xm)
{
    int idx = blockIdx.x * 256 + threadIdx.x;   // < ROWS*512 = 819200
    int c = idx & 511;
    int r = idx >> 9;
    int l = r % LSEQ;

    float w0 = conv_w[c * 4 + 0];
    float w1 = conv_w[c * 4 + 1];
    float w2 = conv_w[c * 4 + 2];
    float w3 = conv_w[c * 4 + 3];

    const float* base = xz + (size_t)r * 1024 + c;
    float acc = conv_b[c];
    if (l >= 3) acc = fmaf(base[-3 * 1024], w0, acc);
    if (l >= 2) acc = fmaf(base[-2 * 1024], w1, acc);
    if (l >= 1) acc = fmaf(base[-1 * 1024], w2, acc);
    acc = fmaf(base[0], w3, acc);

    xm[idx] = siluf(acc);
}

// ---------------------------------------------------------------------------
// C_st[b,l,n] += phase_feats[b,l,:] @ W_phase  (8 MACs), into xp cols 80..143
// ---------------------------------------------------------------------------
__global__ __launch_bounds__(256) void phase_k(
    const float* __restrict__ cosp, const float* __restrict__ sinp,
    const float* __restrict__ W_phase, float* __restrict__ xp)
{
    int idx = blockIdx.x * 256 + threadIdx.x;   // < ROWS*64 = 102400
    int n = idx & 63;
    int r = idx >> 6;
    int b = r / LSEQ, l = r % LSEQ;

    float acc = 0.f;
#pragma unroll
    for (int j = 0; j < 4; j++) {
        float cp = cosp[(b * 4 + j) * LSEQ + l];
        float sp = sinp[(b * 4 + j) * LSEQ + l];
        acc = fmaf(cp, W_phase[j * 64 + n], acc);
        acc = fmaf(sp, W_phase[(4 + j) * 64 + n], acc);
    }
    xp[(size_t)r * 144 + 80 + n] += acc;
}

// ---------------------------------------------------------------------------
// dt = softplus(dt_lr @ W_dt + b_dt) * (1 + softplus(mean(delta_mag)))
// one block per (b,l) row; thread -> 2 channels
// ---------------------------------------------------------------------------
__global__ __launch_bounds__(256) void dt_k(
    const float* __restrict__ xp, const float* __restrict__ W_dt,
    const float* __restrict__ b_dt, const float* __restrict__ dmag,
    float* __restrict__ dtb)
{
    int r = blockIdx.x;          // 0..1599
    int t = threadIdx.x;
    int b = r / LSEQ, l = r % LSEQ;

    __shared__ float xr[16];
    __shared__ float sscale;
    if (t < 16) xr[t] = xp[(size_t)r * 144 + t];
    if (t == 16) {
        float dm = 0.f;
#pragma unroll
        for (int j = 0; j < 4; j++)
            dm += dmag[(b * 4 + j) * LSEQ + l];
        dm *= 0.25f;
        sscale = 1.f + softplusf(dm);
    }
    __syncthreads();
    float scale = sscale;

#pragma unroll
    for (int rep = 0; rep < 2; rep++) {
        int d = t + rep * 256;
        float acc = b_dt[d];
#pragma unroll
        for (int i = 0; i < 16; i++)
            acc = fmaf(xr[i], W_dt[i * 512 + d], acc);
        dtb[(size_t)r * 512 + d] = softplusf(acc) * scale;
    }
}

// ---------------------------------------------------------------------------
// Selective scan: one wave per (b,d), lane = state n (64 states).
// h_l = exp(dt*A)*h_{l-1} + dt*u*B ;  y_l = sum_n h*C ; fused D-skip + z gate
// ---------------------------------------------------------------------------
__global__ __launch_bounds__(256) void scan_k(
    const float* __restrict__ dtb, const float* __restrict__ xm,
    const float* __restrict__ xp, const float* __restrict__ xz,
    const float* __restrict__ A_log, const float* __restrict__ D_skip,
    float* __restrict__ yf)
{
    int wv   = (blockIdx.x * 256 + threadIdx.x) >> 6;   // 0..4095
    int lane = threadIdx.x & 63;
    int b = wv >> 9;        // /512
    int d = wv & 511;

    float A  = -__expf(A_log[d * 64 + lane]);
    float Dd = D_skip[d];

    const float* dtp = dtb + (size_t)b * LSEQ * 512 + d;
    const float* ump = xm  + (size_t)b * LSEQ * 512 + d;
    const float* zp  = xz  + (size_t)b * LSEQ * 1024 + 512 + d;
    const float* xpp = xp  + (size_t)b * LSEQ * 144;
    float*       yp  = yf  + (size_t)b * LSEQ * 512 + d;

    float h = 0.f;
    for (int l = 0; l < LSEQ; l++) {
        float dtv = dtp[l * 512];
        float u   = ump[l * 512];
        float Bv  = xpp[l * 144 + 16 + lane];
        float Cv  = xpp[l * 144 + 80 + lane];

        float e = __expf(dtv * A);
        h = fmaf(e, h, dtv * u * Bv);
        float p = h * Cv;
#pragma unroll
        for (int off = 32; off > 0; off >>= 1) p += __shfl_xor(p, off, 64);

        if (lane == 0) {
            float zv = zp[l * 1024];
            yp[l * 512] = (p + u * Dd) * siluf(zv);
        }
    }
}

// ---------------------------------------------------------------------------
// LayerNorm over last dim (256) + gamma/beta, fp32 out
// ---------------------------------------------------------------------------
__global__ __launch_bounds__(256) void ln_k(
    const float* __restrict__ outp, const float* __restrict__ gamma,
    const float* __restrict__ beta, float* __restrict__ out)
{
    int r = blockIdx.x;
    int t = threadIdx.x;
    float v = outp[(size_t)r * 256 + t];
    float s = v, ss = v * v;
#pragma unroll
    for (int off = 32; off > 0; off >>= 1) {
        s  += __shfl_xor(s,  off, 64);
        ss += __shfl_xor(ss, off, 64);
    }
    __shared__ float red[8];
    int w = t >> 6;
    if ((t & 63) == 0) { red[w] = s; red[4 + w] = ss; }
    __syncthreads();
    s  = red[0] + red[1] + red[2] + red[3];
    ss = red[4] + red[5] + red[6] + red[7];
    float mu  = s * (1.f / 256.f);
    float var = ss * (1.f / 256.f) - mu * mu;
    if (var < 0.f) var = 0.f;
    float inv = rsqrtf(var + 1e-12f);
    float o = (v - mu) * inv * gamma[t] + beta[t];
    out[(size_t)r * 256 + t] = o;
}

// ---------------------------------------------------------------------------
extern "C" void kernel_launch(void* const* d_in, const int* in_sizes, int n_in,
                              void* d_out, int out_size, void* d_ws, size_t ws_size,
                              hipStream_t stream)
{
    const float* x       = (const float*)d_in[0];
    const float* cosp    = (const float*)d_in[1];
    const float* sinp    = (const float*)d_in[2];
    const float* dmag    = (const float*)d_in[3];
    const float* W_in    = (const float*)d_in[4];
    const float* conv_w  = (const float*)d_in[5];
    const float* conv_b  = (const float*)d_in[6];
    const float* W_x     = (const float*)d_in[7];
    const float* W_dt    = (const float*)d_in[8];
    const float* b_dt    = (const float*)d_in[9];
    const float* A_log   = (const float*)d_in[10];
    const float* D_skip  = (const float*)d_in[11];
    const float* W_out   = (const float*)d_in[12];
    const float* gamma   = (const float*)d_in[13];
    const float* beta    = (const float*)d_in[14];
    const float* W_phase = (const float*)d_in[15];
    float* out = (float*)d_out;

    char* ws = (char*)d_ws;
    float* xz   = (float*)ws;  ws += (size_t)ROWS * 1024 * 4;   // xm_raw | z
    float* xm   = (float*)ws;  ws += (size_t)ROWS * 512 * 4;    // post conv+silu
    float* xp   = (float*)ws;  ws += (size_t)ROWS * 144 * 4;    // dt_lr | B_st | C_st
    float* dtb  = (float*)ws;  ws += (size_t)ROWS * 512 * 4;
    float* yf   = (float*)ws;  ws += (size_t)ROWS * 512 * 4;    // gated scan output
    float* outp = (float*)ws;  ws += (size_t)ROWS * 256 * 4;    // pre-LN

    dim3 blk(256);
    gemm_tile <<<dim3(16, 25), blk, 0, stream>>>(x,  W_in,  xz,   ROWS, 1024, 256, nullptr);
    conv_silu_k<<<dim3(3200),  blk, 0, stream>>>(xz, conv_w, conv_b, xm);
    gemm_tile <<<dim3(3, 25),  blk, 0, stream>>>(xm, W_x,   xp,   ROWS, 144,  512, nullptr);
    phase_k   <<<dim3(400),    blk, 0, stream>>>(cosp, sinp, W_phase, xp);
    dt_k      <<<dim3(1600),   blk, 0, stream>>>(xp, W_dt, b_dt, dmag, dtb);
    scan_k    <<<dim3(1024),   blk, 0, stream>>>(dtb, xm, xp, xz, A_log, D_skip, yf);
    gemm_tile <<<dim3(4, 25),  blk, 0, stream>>>(yf, W_out, outp, ROWS, 256,  512, x);
    ln_k      <<<dim3(1600),   blk, 0, stream>>>(outp, gamma, beta, out);
}

// Round 3
// 230.548 us; speedup vs baseline: 1.5544x; 1.5544x over previous
//
#include <hip/hip_runtime.h>
#include <hip/hip_bf16.h>

#define B_SZ 8
#define LSEQ 200
#define DMODEL 256
#define DINNER 512
#define DSTATE 64
#define DTRANK 16
#define ROWS (B_SZ * LSEQ)   // 1600

__device__ __forceinline__ float4 load4f(const float* p) {
    return *(const float4*)p;
}

__device__ __forceinline__ float softplusf(float x) {
    return (x > 20.f) ? x : log1pf(__expf(x));
}
__device__ __forceinline__ float siluf(float x) {
    return x / (1.f + __expf(-x));
}

// ---------------------------------------------------------------------------
// Generic tiled GEMM: C[M,N] = A[M,K] @ B[K,N] (+ optional fp32 residual)
// 64x64 tile, BK=16, 256 threads, 4x4/thread.
// ---------------------------------------------------------------------------
__global__ __launch_bounds__(256) void gemm_tile(
    const float* __restrict__ A, const float* __restrict__ Bm, float* __restrict__ C,
    int M, int N, int K, const float* __restrict__ resid)
{
    __shared__ float As[16][64];
    __shared__ float Bs[16][68];   // +4 pad

    const int t  = threadIdx.x;
    const int m0 = blockIdx.y * 64;
    const int n0 = blockIdx.x * 64;
    const int tm = t >> 4;         // 0..15
    const int tn = t & 15;         // 0..15

    const int ar = t >> 2;         // A staging: row in tile 0..63
    const int ak = (t & 3) * 4;    // A staging: k offset 0,4,8,12
    const int bk = t >> 4;         // B staging: k row 0..15
    const int bn = (t & 15) * 4;   // B staging: n offset 0..60

    float acc[4][4];
#pragma unroll
    for (int i = 0; i < 4; i++)
#pragma unroll
        for (int j = 0; j < 4; j++) acc[i][j] = 0.f;

    for (int k0 = 0; k0 < K; k0 += 16) {
        float4 av = load4f(A + (size_t)(m0 + ar) * K + k0 + ak);
        int col = n0 + bn;
        float4 bv = make_float4(0.f, 0.f, 0.f, 0.f);
        if (col < N) bv = load4f(Bm + (size_t)(k0 + bk) * N + col);

        As[ak + 0][ar] = av.x;
        As[ak + 1][ar] = av.y;
        As[ak + 2][ar] = av.z;
        As[ak + 3][ar] = av.w;
        *(float4*)&Bs[bk][bn] = bv;
        __syncthreads();

#pragma unroll
        for (int k = 0; k < 16; k++) {
            float4 a4 = *(const float4*)&As[k][tm * 4];
            float4 b4 = *(const float4*)&Bs[k][tn * 4];
            float av_[4] = {a4.x, a4.y, a4.z, a4.w};
            float bv_[4] = {b4.x, b4.y, b4.z, b4.w};
#pragma unroll
            for (int i = 0; i < 4; i++)
#pragma unroll
                for (int j = 0; j < 4; j++)
                    acc[i][j] = fmaf(av_[i], bv_[j], acc[i][j]);
        }
        __syncthreads();
    }

#pragma unroll
    for (int i = 0; i < 4; i++) {
        int row = m0 + tm * 4 + i;
#pragma unroll
        for (int j = 0; j < 4; j++) {
            int col = n0 + tn * 4 + j;
            if (col < N) {
                float v = acc[i][j];
                if (resid) v += resid[(size_t)row * N + col];
                C[(size_t)row * N + col] = v;
            }
        }
    }
}

// ---------------------------------------------------------------------------
// Depthwise causal conv (width 4) + bias + silu.  xz cols 0..511 -> xm.
// ---------------------------------------------------------------------------
__global__ __launch_bounds__(256) void conv_silu_k(
    const float* __restrict__ xz, const float* __restrict__ conv_w,
    const float* __restrict__ conv_b, float* __restrict__ xm)
{
    int idx = blockIdx.x * 256 + threadIdx.x;   // < ROWS*512 = 819200
    int c = idx & 511;
    int r = idx >> 9;
    int l = r % LSEQ;

    float w0 = conv_w[c * 4 + 0];
    float w1 = conv_w[c * 4 + 1];
    float w2 = conv_w[c * 4 + 2];
    float w3 = conv_w[c * 4 + 3];

    const float* base = xz + (size_t)r * 1024 + c;
    float acc = conv_b[c];
    if (l >= 3) acc = fmaf(base[-3 * 1024], w0, acc);
    if (l >= 2) acc = fmaf(base[-2 * 1024], w1, acc);
    if (l >= 1) acc = fmaf(base[-1 * 1024], w2, acc);
    acc = fmaf(base[0], w3, acc);

    xm[idx] = siluf(acc);
}

// ---------------------------------------------------------------------------
// Pack B and C (with phase modulation) interleaved per row:
// bcp[r*128 + 2n] = B_st(r,n); bcp[r*128 + 2n+1] = C_st(r,n) + phase
// ---------------------------------------------------------------------------
__global__ __launch_bounds__(256) void pack_bc_k(
    const float* __restrict__ cosp, const float* __restrict__ sinp,
    const float* __restrict__ W_phase, const float* __restrict__ xp,
    float* __restrict__ bcp)
{
    int idx = blockIdx.x * 256 + threadIdx.x;   // < ROWS*64 = 102400
    int n = idx & 63;
    int r = idx >> 6;
    int b = r / LSEQ, l = r % LSEQ;

    float acc = 0.f;
#pragma unroll
    for (int j = 0; j < 4; j++) {
        float cp = cosp[(b * 4 + j) * LSEQ + l];
        float sp = sinp[(b * 4 + j) * LSEQ + l];
        acc = fmaf(cp, W_phase[j * 64 + n], acc);
        acc = fmaf(sp, W_phase[(4 + j) * 64 + n], acc);
    }
    float Bv = xp[(size_t)r * 144 + 16 + n];
    float Cv = xp[(size_t)r * 144 + 80 + n] + acc;
    *(float2*)&bcp[(size_t)r * 128 + 2 * n] = make_float2(Bv, Cv);
}

// ---------------------------------------------------------------------------
// dt = softplus(dt_lr @ W_dt + b_dt) * (1 + softplus(mean(delta_mag)))
// writes dtpack[b][d][l] = (dt, dt*u)   (float2, d-major for the scan)
// ---------------------------------------------------------------------------
__global__ __launch_bounds__(256) void dt_k(
    const float* __restrict__ xp, const float* __restrict__ W_dt,
    const float* __restrict__ b_dt, const float* __restrict__ dmag,
    const float* __restrict__ xm, float2* __restrict__ dtpack)
{
    int r = blockIdx.x;          // 0..1599
    int t = threadIdx.x;
    int b = r / LSEQ, l = r % LSEQ;

    __shared__ float xr[16];
    __shared__ float sscale;
    if (t < 16) xr[t] = xp[(size_t)r * 144 + t];
    if (t == 16) {
        float dm = 0.f;
#pragma unroll
        for (int j = 0; j < 4; j++)
            dm += dmag[(b * 4 + j) * LSEQ + l];
        dm *= 0.25f;
        sscale = 1.f + softplusf(dm);
    }
    __syncthreads();
    float scale = sscale;

#pragma unroll
    for (int rep = 0; rep < 2; rep++) {
        int d = t + rep * 256;
        float acc = b_dt[d];
#pragma unroll
        for (int i = 0; i < 16; i++)
            acc = fmaf(xr[i], W_dt[i * 512 + d], acc);
        float dtv = softplusf(acc) * scale;
        float u = xm[(size_t)r * 512 + d];
        dtpack[((size_t)(b * 512 + d)) * LSEQ + l] = make_float2(dtv, dtv * u);
    }
}

// ---------------------------------------------------------------------------
// Selective scan v2: one wave per (b,d), lane = state n.
// T=8 steps per iteration; deferred reduce-scatter butterfly (10 shfl / 8 steps)
// ---------------------------------------------------------------------------
__global__ __launch_bounds__(256) void scan_k(
    const float2* __restrict__ dtpack, const float* __restrict__ bcp,
    const float* __restrict__ xm, const float* __restrict__ xz,
    const float* __restrict__ A_log, const float* __restrict__ D_skip,
    float* __restrict__ yf)
{
    int wv0  = blockIdx.x * 4 + (threadIdx.x >> 6);      // 0..4095
    int wv   = __builtin_amdgcn_readfirstlane(wv0);      // force SGPR -> s_loads
    int lane = threadIdx.x & 63;
    int b = wv >> 9;        // /512
    int d = wv & 511;

    float A  = -__expf(A_log[d * 64 + lane]);
    float Dd = D_skip[d];

    const float2* dtp  = dtpack + (size_t)(b * 512 + d) * LSEQ;
    const float*  bcr  = bcp + (size_t)b * LSEQ * 128 + 2 * lane;
    const float*  xmb  = xm  + (size_t)b * LSEQ * 512 + d;
    const float*  xzb  = xz  + (size_t)b * LSEQ * 1024 + 512 + d;
    float*        yp   = yf  + (size_t)b * LSEQ * 512 + d;

    const bool lo32 = (lane & 32) == 0;
    const bool lo16 = (lane & 16) == 0;
    const bool lo8  = (lane & 8)  == 0;
    const bool store_lane = (lane & 7) == 0;
    const int  tsel = lane >> 3;

    float h = 0.f;
    for (int l0 = 0; l0 < LSEQ; l0 += 8) {
        // load 8 steps of B/C (coalesced dwordx2) and dt (wave-uniform s_load)
        float2 bc[8], dd[8];
#pragma unroll
        for (int t = 0; t < 8; t++) {
            bc[t] = *(const float2*)&bcr[(size_t)(l0 + t) * 128];
            dd[t] = dtp[l0 + t];
        }

        // recurrence (serial in h, everything else pipelines)
        float p[8];
#pragma unroll
        for (int t = 0; t < 8; t++) {
            float e = __expf(dd[t].x * A);
            h = fmaf(e, h, dd[t].y * bc[t].x);
            p[t] = h * bc[t].y;
        }

        // reduce-scatter butterfly: after this, lane L holds Y[L>>3]
        float q[4];
#pragma unroll
        for (int i = 0; i < 4; i++) {
            float keep = lo32 ? p[i] : p[i + 4];
            float send = lo32 ? p[i + 4] : p[i];
            q[i] = keep + __shfl_xor(send, 32, 64);
        }
        float r2[2];
#pragma unroll
        for (int i = 0; i < 2; i++) {
            float keep = lo16 ? q[i] : q[i + 2];
            float send = lo16 ? q[i + 2] : q[i];
            r2[i] = keep + __shfl_xor(send, 16, 64);
        }
        float keep = lo8 ? r2[0] : r2[1];
        float send = lo8 ? r2[1] : r2[0];
        float s = keep + __shfl_xor(send, 8, 64);
        s += __shfl_xor(s, 4, 64);
        s += __shfl_xor(s, 2, 64);
        s += __shfl_xor(s, 1, 64);

        // epilogue: 8 lanes store y(l0+t) = (Y + u*D) * silu(z)
        if (store_lane) {
            int l = l0 + tsel;
            float u  = xmb[(size_t)l * 512];
            float zv = xzb[(size_t)l * 1024];
            yp[(size_t)l * 512] = (s + u * Dd) * siluf(zv);
        }
    }
}

// ---------------------------------------------------------------------------
// LayerNorm over last dim (256) + gamma/beta, fp32 out
// ---------------------------------------------------------------------------
__global__ __launch_bounds__(256) void ln_k(
    const float* __restrict__ outp, const float* __restrict__ gamma,
    const float* __restrict__ beta, float* __restrict__ out)
{
    int r = blockIdx.x;
    int t = threadIdx.x;
    float v = outp[(size_t)r * 256 + t];
    float s = v, ss = v * v;
#pragma unroll
    for (int off = 32; off > 0; off >>= 1) {
        s  += __shfl_xor(s,  off, 64);
        ss += __shfl_xor(ss, off, 64);
    }
    __shared__ float red[8];
    int w = t >> 6;
    if ((t & 63) == 0) { red[w] = s; red[4 + w] = ss; }
    __syncthreads();
    s  = red[0] + red[1] + red[2] + red[3];
    ss = red[4] + red[5] + red[6] + red[7];
    float mu  = s * (1.f / 256.f);
    float var = ss * (1.f / 256.f) - mu * mu;
    if (var < 0.f) var = 0.f;
    float inv = rsqrtf(var + 1e-12f);
    float o = (v - mu) * inv * gamma[t] + beta[t];
    out[(size_t)r * 256 + t] = o;
}

// ---------------------------------------------------------------------------
extern "C" void kernel_launch(void* const* d_in, const int* in_sizes, int n_in,
                              void* d_out, int out_size, void* d_ws, size_t ws_size,
                              hipStream_t stream)
{
    const float* x       = (const float*)d_in[0];
    const float* cosp    = (const float*)d_in[1];
    const float* sinp    = (const float*)d_in[2];
    const float* dmag    = (const float*)d_in[3];
    const float* W_in    = (const float*)d_in[4];
    const float* conv_w  = (const float*)d_in[5];
    const float* conv_b  = (const float*)d_in[6];
    const float* W_x     = (const float*)d_in[7];
    const float* W_dt    = (const float*)d_in[8];
    const float* b_dt    = (const float*)d_in[9];
    const float* A_log   = (const float*)d_in[10];
    const float* D_skip  = (const float*)d_in[11];
    const float* W_out   = (const float*)d_in[12];
    const float* gamma   = (const float*)d_in[13];
    const float* beta    = (const float*)d_in[14];
    const float* W_phase = (const float*)d_in[15];
    float* out = (float*)d_out;

    char* ws = (char*)d_ws;
    float*  xz     = (float*)ws;  ws += (size_t)ROWS * 1024 * 4;   // x_m raw | z
    float*  xm     = (float*)ws;  ws += (size_t)ROWS * 512 * 4;    // post conv+silu
    float*  xp     = (float*)ws;  ws += (size_t)ROWS * 144 * 4;    // dt_lr | B | C
    float*  bcp    = (float*)ws;  ws += (size_t)ROWS * 128 * 4;    // interleaved B,C
    float2* dtpack = (float2*)ws; ws += (size_t)B_SZ * 512 * LSEQ * 8; // (dt, dt*u)
    float*  yf     = (float*)ws;  ws += (size_t)ROWS * 512 * 4;    // gated scan out
    float*  outp   = (float*)ws;  ws += (size_t)ROWS * 256 * 4;    // pre-LN

    dim3 blk(256);
    gemm_tile  <<<dim3(16, 25), blk, 0, stream>>>(x,  W_in,  xz,   ROWS, 1024, 256, nullptr);
    conv_silu_k<<<dim3(3200),   blk, 0, stream>>>(xz, conv_w, conv_b, xm);
    gemm_tile  <<<dim3(3, 25),  blk, 0, stream>>>(xm, W_x,   xp,   ROWS, 144,  512, nullptr);
    pack_bc_k  <<<dim3(400),    blk, 0, stream>>>(cosp, sinp, W_phase, xp, bcp);
    dt_k       <<<dim3(1600),   blk, 0, stream>>>(xp, W_dt, b_dt, dmag, xm, dtpack);
    scan_k     <<<dim3(1024),   blk, 0, stream>>>(dtpack, bcp, xm, xz, A_log, D_skip, yf);
    gemm_tile  <<<dim3(4, 25),  blk, 0, stream>>>(yf, W_out, outp, ROWS, 256,  512, x);
    ln_k       <<<dim3(1600),   blk, 0, stream>>>(outp, gamma, beta, out);
}

// Round 4
// 185.507 us; speedup vs baseline: 1.9318x; 1.2428x over previous
//
#include <hip/hip_runtime.h>
#include <hip/hip_bf16.h>

#define B_SZ 8
#define LSEQ 200
#define DMODEL 256
#define DINNER 512
#define DSTATE 64
#define DTRANK 16
#define ROWS (B_SZ * LSEQ)   // 1600

using bf16x8 = __attribute__((ext_vector_type(8))) short;
using f32x4  = __attribute__((ext_vector_type(4))) float;

__device__ __forceinline__ float softplusf(float x) {
    return (x > 20.f) ? x : log1pf(__expf(x));
}
__device__ __forceinline__ float siluf(float x) {
    return x / (1.f + __expf(-x));
}
__device__ __forceinline__ unsigned short f2bf(float f) {
    union { float f; unsigned int u; } v; v.f = f;
    unsigned int r = v.u + 0x7FFF + ((v.u >> 16) & 1);   // RNE
    return (unsigned short)(r >> 16);
}
__device__ __forceinline__ float bf2f(unsigned short u) {
    union { unsigned int i; float f; } v;
    v.i = ((unsigned int)u) << 16;
    return v.f;
}

// ---------------------------------------------------------------------------
// One-time prep: split x into bf16 hi/lo; transpose+split W_in, W_x, W_out
// into [N][K] k-contiguous bf16 hi/lo (B-operand layout for MFMA).
// ---------------------------------------------------------------------------
__global__ __launch_bounds__(256) void prep_w_k(
    const float* __restrict__ x, const float* __restrict__ W_in,
    const float* __restrict__ W_x, const float* __restrict__ W_out,
    unsigned short* __restrict__ x_hi,  unsigned short* __restrict__ x_lo,
    unsigned short* __restrict__ WiT_hi, unsigned short* __restrict__ WiT_lo,
    unsigned short* __restrict__ WxT_hi, unsigned short* __restrict__ WxT_lo,
    unsigned short* __restrict__ WoT_hi, unsigned short* __restrict__ WoT_lo)
{
    int idx = blockIdx.x * 256 + threadIdx.x;
    float v;
    unsigned short *dh, *dl;
    size_t di;
    if (idx < 409600) {                       // x: straight split (k-contig already)
        v = x[idx]; dh = x_hi; dl = x_lo; di = idx;
    } else if (idx < 409600 + 262144) {       // W_in [256][1024] -> WiT [1024][256]
        int l = idx - 409600;
        int n = l >> 8, k = l & 255;
        v = W_in[(size_t)k * 1024 + n]; dh = WiT_hi; dl = WiT_lo; di = l;  // l == n*256+k
    } else if (idx < 409600 + 262144 + 73728) { // W_x [512][144] -> WxT [144][512]
        int l = idx - (409600 + 262144);
        int n = l >> 9, k = l & 511;
        v = W_x[(size_t)k * 144 + n]; dh = WxT_hi; dl = WxT_lo; di = l;    // l == n*512+k
    } else if (idx < 409600 + 262144 + 73728 + 131072) { // W_out [512][256] -> WoT [256][512]
        int l = idx - (409600 + 262144 + 73728);
        int n = l >> 9, k = l & 511;
        v = W_out[(size_t)k * 256 + n]; dh = WoT_hi; dl = WoT_lo; di = l;  // l == n*512+k
    } else return;
    unsigned short h = f2bf(v);
    dh[di] = h;
    dl[di] = f2bf(v - bf2f(h));
}

// ---------------------------------------------------------------------------
// Split-bf16 MFMA GEMM: C[M,N] = A[M,K]·B[K,N] (+resid), fp32-accurate via
// hi·hi + hi·lo + lo·hi. A as split bf16 [M][K]; B as split bf16 [N][K]
// (transposed, k-contig). 64x64 block tile, 4 waves of 32x32, BK=32.
// M mult of 64, K mult of 32, N guarded.
// ---------------------------------------------------------------------------
__global__ __launch_bounds__(256) void gemm_mfma(
    const unsigned short* __restrict__ A_hi, const unsigned short* __restrict__ A_lo,
    const unsigned short* __restrict__ BT_hi, const unsigned short* __restrict__ BT_lo,
    float* __restrict__ C, int M, int N, int K, const float* __restrict__ resid)
{
    __shared__ unsigned short As_hi[64 * 40], As_lo[64 * 40];  // row stride 40 bf16
    __shared__ unsigned short Bs_hi[64 * 40], Bs_lo[64 * 40];

    const int t    = threadIdx.x;
    const int m0   = blockIdx.y * 64;
    const int n0   = blockIdx.x * 64;
    const int lane = t & 63;
    const int w    = t >> 6;
    const int wm   = (w >> 1) * 32;
    const int wn   = (w & 1) * 32;
    const int fr   = lane & 15;     // frag m (A) / n (B) index
    const int fq   = lane >> 4;     // frag quad: k-offset fq*8; D-row fq*4+reg

    const int sr = t >> 2;          // staging row 0..63
    const int sc = (t & 3) * 8;     // staging col 0,8,16,24

    f32x4 acc[2][2] = {};

    const size_t a_off = (size_t)(m0 + sr) * K + sc;
    const int    brow  = n0 + sr;
    const size_t b_off = (size_t)brow * K + sc;
    const bool   bok   = brow < N;

    for (int k0 = 0; k0 < K; k0 += 32) {
        int4 ah = *(const int4*)(A_hi + a_off + k0);
        int4 al = *(const int4*)(A_lo + a_off + k0);
        int4 bh = make_int4(0, 0, 0, 0), bl = make_int4(0, 0, 0, 0);
        if (bok) {
            bh = *(const int4*)(BT_hi + b_off + k0);
            bl = *(const int4*)(BT_lo + b_off + k0);
        }
        __syncthreads();   // previous iteration's frag reads done
        *(int4*)&As_hi[sr * 40 + sc] = ah;
        *(int4*)&As_lo[sr * 40 + sc] = al;
        *(int4*)&Bs_hi[sr * 40 + sc] = bh;
        *(int4*)&Bs_lo[sr * 40 + sc] = bl;
        __syncthreads();

        bf16x8 a_h[2], a_l[2], b_h[2], b_l[2];
#pragma unroll
        for (int mi = 0; mi < 2; mi++) {
            int row = wm + mi * 16 + fr;
            a_h[mi] = *(const bf16x8*)&As_hi[row * 40 + fq * 8];
            a_l[mi] = *(const bf16x8*)&As_lo[row * 40 + fq * 8];
        }
#pragma unroll
        for (int ni = 0; ni < 2; ni++) {
            int row = wn + ni * 16 + fr;
            b_h[ni] = *(const bf16x8*)&Bs_hi[row * 40 + fq * 8];
            b_l[ni] = *(const bf16x8*)&Bs_lo[row * 40 + fq * 8];
        }
#pragma unroll
        for (int mi = 0; mi < 2; mi++)
#pragma unroll
            for (int ni = 0; ni < 2; ni++) {
                acc[mi][ni] = __builtin_amdgcn_mfma_f32_16x16x32_bf16(a_h[mi], b_h[ni], acc[mi][ni], 0, 0, 0);
                acc[mi][ni] = __builtin_amdgcn_mfma_f32_16x16x32_bf16(a_h[mi], b_l[ni], acc[mi][ni], 0, 0, 0);
                acc[mi][ni] = __builtin_amdgcn_mfma_f32_16x16x32_bf16(a_l[mi], b_h[ni], acc[mi][ni], 0, 0, 0);
            }
    }

#pragma unroll
    for (int mi = 0; mi < 2; mi++)
#pragma unroll
        for (int ni = 0; ni < 2; ni++) {
            int col = n0 + wn + ni * 16 + fr;
            if (col < N) {
#pragma unroll
                for (int reg = 0; reg < 4; reg++) {
                    int row = m0 + wm + mi * 16 + fq * 4 + reg;
                    float v = acc[mi][ni][reg];
                    if (resid) v += resid[(size_t)row * N + col];
                    C[(size_t)row * N + col] = v;
                }
            }
        }
}

// ---------------------------------------------------------------------------
// Depthwise causal conv (width 4) + bias + silu; emits fp32 + split bf16.
// ---------------------------------------------------------------------------
__global__ __launch_bounds__(256) void conv_silu_k(
    const float* __restrict__ xz, const float* __restrict__ conv_w,
    const float* __restrict__ conv_b, float* __restrict__ xm,
    unsigned short* __restrict__ xm_hi, unsigned short* __restrict__ xm_lo)
{
    int idx = blockIdx.x * 256 + threadIdx.x;   // < ROWS*512 = 819200
    int c = idx & 511;
    int r = idx >> 9;
    int l = r % LSEQ;

    float w0 = conv_w[c * 4 + 0];
    float w1 = conv_w[c * 4 + 1];
    float w2 = conv_w[c * 4 + 2];
    float w3 = conv_w[c * 4 + 3];

    const float* base = xz + (size_t)r * 1024 + c;
    float acc = conv_b[c];
    if (l >= 3) acc = fmaf(base[-3 * 1024], w0, acc);
    if (l >= 2) acc = fmaf(base[-2 * 1024], w1, acc);
    if (l >= 1) acc = fmaf(base[-1 * 1024], w2, acc);
    acc = fmaf(base[0], w3, acc);

    float s = siluf(acc);
    xm[idx] = s;
    unsigned short h = f2bf(s);
    xm_hi[idx] = h;
    xm_lo[idx] = f2bf(s - bf2f(h));
}

// ---------------------------------------------------------------------------
// Pack B and C (with phase modulation) interleaved per row.
// ---------------------------------------------------------------------------
__global__ __launch_bounds__(256) void pack_bc_k(
    const float* __restrict__ cosp, const float* __restrict__ sinp,
    const float* __restrict__ W_phase, const float* __restrict__ xp,
    float* __restrict__ bcp)
{
    int idx = blockIdx.x * 256 + threadIdx.x;   // < ROWS*64 = 102400
    int n = idx & 63;
    int r = idx >> 6;
    int b = r / LSEQ, l = r % LSEQ;

    float acc = 0.f;
#pragma unroll
    for (int j = 0; j < 4; j++) {
        float cp = cosp[(b * 4 + j) * LSEQ + l];
        float sp = sinp[(b * 4 + j) * LSEQ + l];
        acc = fmaf(cp, W_phase[j * 64 + n], acc);
        acc = fmaf(sp, W_phase[(4 + j) * 64 + n], acc);
    }
    float Bv = xp[(size_t)r * 144 + 16 + n];
    float Cv = xp[(size_t)r * 144 + 80 + n] + acc;
    *(float2*)&bcp[(size_t)r * 128 + 2 * n] = make_float2(Bv, Cv);
}

// ---------------------------------------------------------------------------
// dt kernel; writes dtpack[r*512+d] = (dt, dt*u)  -- l-major, coalesced.
// ---------------------------------------------------------------------------
__global__ __launch_bounds__(256) void dt_k(
    const float* __restrict__ xp, const float* __restrict__ W_dt,
    const float* __restrict__ b_dt, const float* __restrict__ dmag,
    const float* __restrict__ xm, float2* __restrict__ dtpack)
{
    int r = blockIdx.x;          // 0..1599
    int t = threadIdx.x;
    int b = r / LSEQ, l = r % LSEQ;

    __shared__ float xr[16];
    __shared__ float sscale;
    if (t < 16) xr[t] = xp[(size_t)r * 144 + t];
    if (t == 16) {
        float dm = 0.f;
#pragma unroll
        for (int j = 0; j < 4; j++)
            dm += dmag[(b * 4 + j) * LSEQ + l];
        dm *= 0.25f;
        sscale = 1.f + softplusf(dm);
    }
    __syncthreads();
    float scale = sscale;

#pragma unroll
    for (int rep = 0; rep < 2; rep++) {
        int d = t + rep * 256;
        float acc = b_dt[d];
#pragma unroll
        for (int i = 0; i < 16; i++)
            acc = fmaf(xr[i], W_dt[i * 512 + d], acc);
        float dtv = softplusf(acc) * scale;
        float u = xm[(size_t)r * 512 + d];
        dtpack[(size_t)r * 512 + d] = make_float2(dtv, dtv * u);
    }
}

// ---------------------------------------------------------------------------
// Selective scan: one wave per (b,d), lane = state n; T=8 steps/iter with
// deferred reduce-scatter butterfly. Emits yf fp32 + split bf16.
// ---------------------------------------------------------------------------
__global__ __launch_bounds__(256) void scan_k(
    const float2* __restrict__ dtpack, const float* __restrict__ bcp,
    const float* __restrict__ xm, const float* __restrict__ xz,
    const float* __restrict__ A_log, const float* __restrict__ D_skip,
    float* __restrict__ yf,
    unsigned short* __restrict__ yf_hi, unsigned short* __restrict__ yf_lo)
{
    int wv0  = blockIdx.x * 4 + (threadIdx.x >> 6);      // 0..4095
    int wv   = __builtin_amdgcn_readfirstlane(wv0);
    int lane = threadIdx.x & 63;
    int b = wv >> 9;
    int d = wv & 511;

    float A  = -__expf(A_log[d * 64 + lane]);
    float Dd = D_skip[d];

    const float2* dtp = dtpack + (size_t)b * LSEQ * 512 + d;
    const float*  bcr = bcp + (size_t)b * LSEQ * 128 + 2 * lane;
    const float*  xmb = xm  + (size_t)b * LSEQ * 512 + d;
    const float*  xzb = xz  + (size_t)b * LSEQ * 1024 + 512 + d;
    float*          yp  = yf    + (size_t)b * LSEQ * 512 + d;
    unsigned short* yph = yf_hi + (size_t)b * LSEQ * 512 + d;
    unsigned short* ypl = yf_lo + (size_t)b * LSEQ * 512 + d;

    const bool lo32 = (lane & 32) == 0;
    const bool lo16 = (lane & 16) == 0;
    const bool lo8  = (lane & 8)  == 0;
    const bool store_lane = (lane & 7) == 0;
    const int  tsel = lane >> 3;

    float h = 0.f;
    for (int l0 = 0; l0 < LSEQ; l0 += 8) {
        float2 bc[8], dd[8];
#pragma unroll
        for (int t = 0; t < 8; t++) {
            bc[t] = *(const float2*)&bcr[(size_t)(l0 + t) * 128];
            dd[t] = dtp[(size_t)(l0 + t) * 512];
        }

        float p[8];
#pragma unroll
        for (int t = 0; t < 8; t++) {
            float e = __expf(dd[t].x * A);
            h = fmaf(e, h, dd[t].y * bc[t].x);
            p[t] = h * bc[t].y;
        }

        float q[4];
#pragma unroll
        for (int i = 0; i < 4; i++) {
            float keep = lo32 ? p[i] : p[i + 4];
            float send = lo32 ? p[i + 4] : p[i];
            q[i] = keep + __shfl_xor(send, 32, 64);
        }
        float r2[2];
#pragma unroll
        for (int i = 0; i < 2; i++) {
            float keep = lo16 ? q[i] : q[i + 2];
            float send = lo16 ? q[i + 2] : q[i];
            r2[i] = keep + __shfl_xor(send, 16, 64);
        }
        float keep = lo8 ? r2[0] : r2[1];
        float send = lo8 ? r2[1] : r2[0];
        float s = keep + __shfl_xor(send, 8, 64);
        s += __shfl_xor(s, 4, 64);
        s += __shfl_xor(s, 2, 64);
        s += __shfl_xor(s, 1, 64);

        if (store_lane) {
            int l = l0 + tsel;
            float u  = xmb[(size_t)l * 512];
            float zv = xzb[(size_t)l * 1024];
            float yv = (s + u * Dd) * siluf(zv);
            yp[(size_t)l * 512] = yv;
            unsigned short hh = f2bf(yv);
            yph[(size_t)l * 512] = hh;
            ypl[(size_t)l * 512] = f2bf(yv - bf2f(hh));
        }
    }
}

// ---------------------------------------------------------------------------
// LayerNorm over last dim (256) + gamma/beta, fp32 out
// ---------------------------------------------------------------------------
__global__ __launch_bounds__(256) void ln_k(
    const float* __restrict__ outp, const float* __restrict__ gamma,
    const float* __restrict__ beta, float* __restrict__ out)
{
    int r = blockIdx.x;
    int t = threadIdx.x;
    float v = outp[(size_t)r * 256 + t];
    float s = v, ss = v * v;
#pragma unroll
    for (int off = 32; off > 0; off >>= 1) {
        s  += __shfl_xor(s,  off, 64);
        ss += __shfl_xor(ss, off, 64);
    }
    __shared__ float red[8];
    int w = t >> 6;
    if ((t & 63) == 0) { red[w] = s; red[4 + w] = ss; }
    __syncthreads();
    s  = red[0] + red[1] + red[2] + red[3];
    ss = red[4] + red[5] + red[6] + red[7];
    float mu  = s * (1.f / 256.f);
    float var = ss * (1.f / 256.f) - mu * mu;
    if (var < 0.f) var = 0.f;
    float inv = rsqrtf(var + 1e-12f);
    float o = (v - mu) * inv * gamma[t] + beta[t];
    out[(size_t)r * 256 + t] = o;
}

// ---------------------------------------------------------------------------
extern "C" void kernel_launch(void* const* d_in, const int* in_sizes, int n_in,
                              void* d_out, int out_size, void* d_ws, size_t ws_size,
                              hipStream_t stream)
{
    const float* x       = (const float*)d_in[0];
    const float* cosp    = (const float*)d_in[1];
    const float* sinp    = (const float*)d_in[2];
    const float* dmag    = (const float*)d_in[3];
    const float* W_in    = (const float*)d_in[4];
    const float* conv_w  = (const float*)d_in[5];
    const float* conv_b  = (const float*)d_in[6];
    const float* W_x     = (const float*)d_in[7];
    const float* W_dt    = (const float*)d_in[8];
    const float* b_dt    = (const float*)d_in[9];
    const float* A_log   = (const float*)d_in[10];
    const float* D_skip  = (const float*)d_in[11];
    const float* W_out   = (const float*)d_in[12];
    const float* gamma   = (const float*)d_in[13];
    const float* beta    = (const float*)d_in[14];
    const float* W_phase = (const float*)d_in[15];
    float* out = (float*)d_out;

    char* ws = (char*)d_ws;
    float*  xz     = (float*)ws;  ws += (size_t)ROWS * 1024 * 4;
    float*  xm     = (float*)ws;  ws += (size_t)ROWS * 512 * 4;
    float*  xp     = (float*)ws;  ws += (size_t)ROWS * 144 * 4;
    float*  bcp    = (float*)ws;  ws += (size_t)ROWS * 128 * 4;
    float2* dtpack = (float2*)ws; ws += (size_t)ROWS * 512 * 8;
    float*  yf     = (float*)ws;  ws += (size_t)ROWS * 512 * 4;
    float*  outp   = (float*)ws;  ws += (size_t)ROWS * 256 * 4;
    unsigned short* x_hi   = (unsigned short*)ws; ws += (size_t)ROWS * 256 * 2;
    unsigned short* x_lo   = (unsigned short*)ws; ws += (size_t)ROWS * 256 * 2;
    unsigned short* WiT_hi = (unsigned short*)ws; ws += (size_t)1024 * 256 * 2;
    unsigned short* WiT_lo = (unsigned short*)ws; ws += (size_t)1024 * 256 * 2;
    unsigned short* WxT_hi = (unsigned short*)ws; ws += (size_t)144 * 512 * 2;
    unsigned short* WxT_lo = (unsigned short*)ws; ws += (size_t)144 * 512 * 2;
    unsigned short* WoT_hi = (unsigned short*)ws; ws += (size_t)256 * 512 * 2;
    unsigned short* WoT_lo = (unsigned short*)ws; ws += (size_t)256 * 512 * 2;
    unsigned short* xm_hi  = (unsigned short*)ws; ws += (size_t)ROWS * 512 * 2;
    unsigned short* xm_lo  = (unsigned short*)ws; ws += (size_t)ROWS * 512 * 2;
    unsigned short* yf_hi  = (unsigned short*)ws; ws += (size_t)ROWS * 512 * 2;
    unsigned short* yf_lo  = (unsigned short*)ws; ws += (size_t)ROWS * 512 * 2;

    dim3 blk(256);
    prep_w_k   <<<dim3(3424),   blk, 0, stream>>>(x, W_in, W_x, W_out,
                                                  x_hi, x_lo, WiT_hi, WiT_lo,
                                                  WxT_hi, WxT_lo, WoT_hi, WoT_lo);
    gemm_mfma  <<<dim3(16, 25), blk, 0, stream>>>(x_hi, x_lo, WiT_hi, WiT_lo,
                                                  xz, ROWS, 1024, 256, nullptr);
    conv_silu_k<<<dim3(3200),   blk, 0, stream>>>(xz, conv_w, conv_b, xm, xm_hi, xm_lo);
    gemm_mfma  <<<dim3(3, 25),  blk, 0, stream>>>(xm_hi, xm_lo, WxT_hi, WxT_lo,
                                                  xp, ROWS, 144, 512, nullptr);
    pack_bc_k  <<<dim3(400),    blk, 0, stream>>>(cosp, sinp, W_phase, xp, bcp);
    dt_k       <<<dim3(1600),   blk, 0, stream>>>(xp, W_dt, b_dt, dmag, xm, dtpack);
    scan_k     <<<dim3(1024),   blk, 0, stream>>>(dtpack, bcp, xm, xz, A_log, D_skip,
                                                  yf, yf_hi, yf_lo);
    gemm_mfma  <<<dim3(4, 25),  blk, 0, stream>>>(yf_hi, yf_lo, WoT_hi, WoT_lo,
                                                  outp, ROWS, 256, 512, x);
    ln_k       <<<dim3(1600),   blk, 0, stream>>>(outp, gamma, beta, out);
}